// Round 2
// baseline (478.176 us; speedup 1.0000x reference)
//
#include <hip/hip_runtime.h>
#include <cstdint>
#include <cstddef>

// GCN: N=512 nodes, B=64 batch, F=O=128, E=3 edge channels, 2 layers.
// ALL tensors fp32 in memory (per reference dtypes). Compute via bf16 MFMA
// (fp32 accumulate); 2%-absmax tolerance admits bf16 rounding comfortably.
//
// Layouts:
//   x / h(out) : [N,B,O] fp32, flat row r = n*64+b, o contiguous
//   adj        : [E,B,N,N] fp32, n contiguous
//   sup (ws)   : [E,B,O,N] bf16, n contiguous (transposed so k_agg's MFMA
//                B-operand reads contiguous-k with ds_read_b128)
//   tg  (ws)   : [r,o] fp32 gate = sigmoid(x@Wh+bh)
// Layer-1 output h lives in d_out (fp32); layer 2 reads it and overwrites
// d_out in-place (epilogue read+write of the same index by the same thread).

typedef __bf16 bf16x8 __attribute__((ext_vector_type(8)));
typedef float f32x4 __attribute__((ext_vector_type(4)));

#define MFMA16(a, b, c) __builtin_amdgcn_mfma_f32_16x16x32_bf16((a), (b), (c), 0, 0, 0)

__device__ __forceinline__ unsigned short f2bf(float f) {  // round-nearest-even
  union { float f; unsigned int i; } v;
  v.f = f;
  return (unsigned short)((v.i + 0x7FFFu + ((v.i >> 16) & 1u)) >> 16);
}

// ---------------------------------------------------------------------------
// k_support: sup[e,b,o,n] = sum_f W[e,f,o]*x[n,b,f] + bias[e,o]   (bf16 out)
// GEMM per (b, n-tile): D[o,n] = W^T[o,f] @ X^T[f,n]. M=o(128),N=n(128),K=f(128)
// grid (4, 64), 256 threads (4 waves, 2x2 wave tile of 64x64)
// ---------------------------------------------------------------------------
__global__ __launch_bounds__(256) void k_support(
    const float* __restrict__ x, const float* __restrict__ W,
    const float* __restrict__ bias, unsigned short* __restrict__ sup) {
  __shared__ unsigned short Xs[128 * 136];  // [n][f] bf16, pad 136
  __shared__ unsigned short Wt[128 * 136];  // [o][f] = W[e]^T bf16
  const int tid = threadIdx.x;
  const int lane = tid & 63;
  const int wv = tid >> 6;
  const int wm = wv >> 1, wn = wv & 1;
  const int l15 = lane & 15, q = lane >> 4;
  const int b = blockIdx.y;
  const int n0 = blockIdx.x * 128;

  // Stage Xs[n][f] = bf16(x[(n0+n)*8192 + b*128 + f])
  {
    const size_t base = (size_t)n0 * 8192 + (size_t)b * 128;
#pragma unroll
    for (int i = 0; i < 16; ++i) {
      int c = i * 256 + tid;   // 4096 float4-chunks
      int n = c >> 5;
      int p = (c & 31) * 4;
      float4 v = *(const float4*)(x + base + (size_t)n * 8192 + p);
      ushort4 u = { f2bf(v.x), f2bf(v.y), f2bf(v.z), f2bf(v.w) };
      *(ushort4*)(&Xs[n * 136 + p]) = u;
    }
  }

  for (int e = 0; e < 3; ++e) {
    __syncthreads();  // fence Xs stage (e=0) / previous e's Wt reads
    {
      int o = tid & 127, fh = tid >> 7;
      const float* wp = W + e * 16384 + o;
      for (int f = fh; f < 128; f += 2) Wt[o * 136 + f] = f2bf(wp[f * 128]);
    }
    __syncthreads();

    f32x4 acc[4][4];
#pragma unroll
    for (int i = 0; i < 4; ++i)
#pragma unroll
      for (int j = 0; j < 4; ++j) acc[i][j] = (f32x4){0.f, 0.f, 0.f, 0.f};

#pragma unroll
    for (int kt = 0; kt < 4; ++kt) {
      bf16x8 a[4], bb[4];
#pragma unroll
      for (int mt = 0; mt < 4; ++mt)
        a[mt] = *(const bf16x8*)(&Wt[(wm * 64 + mt * 16 + l15) * 136 + kt * 32 + q * 8]);
#pragma unroll
      for (int nt = 0; nt < 4; ++nt)
        bb[nt] = *(const bf16x8*)(&Xs[(wn * 64 + nt * 16 + l15) * 136 + kt * 32 + q * 8]);
#pragma unroll
      for (int mt = 0; mt < 4; ++mt)
#pragma unroll
        for (int nt = 0; nt < 4; ++nt)
          acc[mt][nt] = MFMA16(a[mt], bb[nt], acc[mt][nt]);
    }

    // Epilogue: C row=o (quad*4+reg), col=n (l15). Store bf16, n-contiguous.
    const size_t sb = (size_t)(e * 64 + b) * 128 * 512;
#pragma unroll
    for (int mt = 0; mt < 4; ++mt) {
      int o = wm * 64 + mt * 16 + q * 4;
#pragma unroll
      for (int nt = 0; nt < 4; ++nt) {
        int nn = n0 + wn * 64 + nt * 16 + l15;
#pragma unroll
        for (int r = 0; r < 4; ++r) {
          float v = acc[mt][nt][r] + bias[e * 128 + o + r];
          sup[sb + (size_t)(o + r) * 512 + nn] = f2bf(v);
        }
      }
    }
  }
}

// ---------------------------------------------------------------------------
// k_gate: tg[r,o] = sigmoid( sum_f x[r,f]*Wh[f,o] + bh[o] ),  r = n*64+b
// grid 256 (r-tiles of 128), 256 threads, 2x2 wave tile. fp32 output.
// ---------------------------------------------------------------------------
__global__ __launch_bounds__(256) void k_gate(
    const float* __restrict__ x, const float* __restrict__ Wh,
    const float* __restrict__ bh, float* __restrict__ tg) {
  __shared__ unsigned short Xs[128 * 136];  // [r][f]
  __shared__ unsigned short Wt[128 * 136];  // [o][f] = Wh^T
  const int tid = threadIdx.x;
  const int lane = tid & 63;
  const int wv = tid >> 6;
  const int wm = wv >> 1, wn = wv & 1;
  const int l15 = lane & 15, q = lane >> 4;
  const size_t r0 = (size_t)blockIdx.x * 128;

#pragma unroll
  for (int i = 0; i < 16; ++i) {
    int c = i * 256 + tid;
    int rr = c >> 5;
    int p = (c & 31) * 4;
    float4 v = *(const float4*)(x + (r0 + rr) * 128 + p);
    ushort4 u = { f2bf(v.x), f2bf(v.y), f2bf(v.z), f2bf(v.w) };
    *(ushort4*)(&Xs[rr * 136 + p]) = u;
  }
  {
    int o = tid & 127, fh = tid >> 7;
    for (int f = fh; f < 128; f += 2) Wt[o * 136 + f] = f2bf(Wh[f * 128 + o]);
  }
  __syncthreads();

  f32x4 acc[4][4];
#pragma unroll
  for (int i = 0; i < 4; ++i)
#pragma unroll
    for (int j = 0; j < 4; ++j) acc[i][j] = (f32x4){0.f, 0.f, 0.f, 0.f};

#pragma unroll
  for (int kt = 0; kt < 4; ++kt) {
    bf16x8 a[4], bb[4];
#pragma unroll
    for (int mt = 0; mt < 4; ++mt)
      a[mt] = *(const bf16x8*)(&Xs[(wm * 64 + mt * 16 + l15) * 136 + kt * 32 + q * 8]);
#pragma unroll
    for (int nt = 0; nt < 4; ++nt)
      bb[nt] = *(const bf16x8*)(&Wt[(wn * 64 + nt * 16 + l15) * 136 + kt * 32 + q * 8]);
#pragma unroll
    for (int mt = 0; mt < 4; ++mt)
#pragma unroll
      for (int nt = 0; nt < 4; ++nt)
        acc[mt][nt] = MFMA16(a[mt], bb[nt], acc[mt][nt]);
  }

#pragma unroll
  for (int mt = 0; mt < 4; ++mt) {
#pragma unroll
    for (int nt = 0; nt < 4; ++nt) {
      int o = wn * 64 + nt * 16 + l15;
#pragma unroll
      for (int r = 0; r < 4; ++r) {
        size_t rr = r0 + wm * 64 + mt * 16 + q * 4 + r;
        float v = acc[mt][nt][r] + bh[o];
        tg[rr * 128 + o] = 1.f / (1.f + __expf(-v));
      }
    }
  }
}

// ---------------------------------------------------------------------------
// k_agg: dst[m,b,o] = relu( sum_e sum_n adj[e,b,m,n]*sup[e,b,o,n] ) * t
//        + x[m,b,o]*(1-t),  t = tg[m*64+b, o]
// grid (8, 64): (m-tile of 64, b). 256 threads, wave w -> m rows [16w,16w+16)
// ---------------------------------------------------------------------------
__global__ __launch_bounds__(256) void k_agg(
    const float* __restrict__ adj, const unsigned short* __restrict__ sup,
    const float* __restrict__ tg, const float* __restrict__ x,
    float* __restrict__ dst) {
  __shared__ unsigned short As[64 * 40];   // adj tile [m][n-chunk] bf16, pad 40
  __shared__ unsigned short Bs[128 * 40];  // sup tile [o][n-chunk] bf16
  const int tid = threadIdx.x;
  const int lane = tid & 63;
  const int wv = tid >> 6;
  const int l15 = lane & 15, q = lane >> 4;
  const int b = blockIdx.y;
  const int m0 = blockIdx.x * 64;

  f32x4 acc[8];
#pragma unroll
  for (int i = 0; i < 8; ++i) acc[i] = (f32x4){0.f, 0.f, 0.f, 0.f};

  for (int e = 0; e < 3; ++e) {
    const size_t abase = ((size_t)(e * 64 + b) * 512 + m0) * 512;
    const size_t sbase = (size_t)(e * 64 + b) * 128 * 512;
    for (int kt = 0; kt < 16; ++kt) {
      __syncthreads();  // previous step's LDS reads done before restage
      {
        int row = tid >> 2, c = tid & 3;
        const float* ap = adj + abase + (size_t)row * 512 + kt * 32 + c * 8;
        float4 v0 = *(const float4*)ap;
        float4 v1 = *(const float4*)(ap + 4);
        ushort4 u0 = { f2bf(v0.x), f2bf(v0.y), f2bf(v0.z), f2bf(v0.w) };
        ushort4 u1 = { f2bf(v1.x), f2bf(v1.y), f2bf(v1.z), f2bf(v1.w) };
        *(ushort4*)(&As[row * 40 + c * 8]) = u0;
        *(ushort4*)(&As[row * 40 + c * 8 + 4]) = u1;
#pragma unroll
        for (int i = 0; i < 2; ++i) {
          int idx = i * 256 + tid;
          int o = idx >> 2, cc = idx & 3;
          *(uint4*)(&Bs[o * 40 + cc * 8]) =
              *(const uint4*)(sup + sbase + (size_t)o * 512 + kt * 32 + cc * 8);
        }
      }
      __syncthreads();
      bf16x8 a = *(const bf16x8*)(&As[(wv * 16 + l15) * 40 + q * 8]);
#pragma unroll
      for (int ot = 0; ot < 8; ++ot) {
        bf16x8 bb = *(const bf16x8*)(&Bs[(ot * 16 + l15) * 40 + q * 8]);
        acc[ot] = MFMA16(a, bb, acc[ot]);
      }
    }
  }

  // Epilogue: relu + highway blend. C row=m (quad*4+reg), col=o (l15).
#pragma unroll
  for (int ot = 0; ot < 8; ++ot) {
#pragma unroll
    for (int r = 0; r < 4; ++r) {
      int m = m0 + wv * 16 + q * 4 + r;
      int o = ot * 16 + l15;
      size_t ridx = (size_t)(m * 64 + b) * 128 + o;
      float agg = acc[ot][r];
      agg = agg > 0.f ? agg : 0.f;
      float tv = tg[ridx];
      float xv = x[ridx];
      dst[ridx] = fmaf(agg, tv, xv * (1.f - tv));
    }
  }
}

// ---------------------------------------------------------------------------
extern "C" void kernel_launch(void* const* d_in, const int* in_sizes, int n_in,
                              void* d_out, int out_size, void* d_ws, size_t ws_size,
                              hipStream_t stream) {
  const float* x   = (const float*)d_in[0];
  const float* adj = (const float*)d_in[1];
  const float* W1  = (const float*)d_in[2];
  const float* b1  = (const float*)d_in[3];
  const float* Wh1 = (const float*)d_in[4];
  const float* bh1 = (const float*)d_in[5];
  const float* W2  = (const float*)d_in[6];
  const float* b2  = (const float*)d_in[7];
  const float* Wh2 = (const float*)d_in[8];
  const float* bh2 = (const float*)d_in[9];
  float* out = (float*)d_out;

  char* ws = (char*)d_ws;
  unsigned short* sup = (unsigned short*)ws;        // 3*64*128*512*2 = 25,165,824 B
  float* tg = (float*)(ws + 25165824);              // 32768*128*4   = 16,777,216 B

  dim3 blk(256);

  // Layer 1 (h goes to d_out)
  k_support<<<dim3(4, 64), blk, 0, stream>>>(x, W1, b1, sup);
  k_gate<<<dim3(256), blk, 0, stream>>>(x, Wh1, bh1, tg);
  k_agg<<<dim3(8, 64), blk, 0, stream>>>(adj, sup, tg, x, out);

  // Layer 2 (in-place on d_out)
  k_support<<<dim3(4, 64), blk, 0, stream>>>(out, W2, b2, sup);
  k_gate<<<dim3(256), blk, 0, stream>>>(out, Wh2, bh2, tg);
  k_agg<<<dim3(8, 64), blk, 0, stream>>>(adj, sup, tg, out, out);
}

// Round 3
// 445.752 us; speedup vs baseline: 1.0727x; 1.0727x over previous
//
#include <hip/hip_runtime.h>
#include <cstdint>
#include <cstddef>

// GCN: N=512, B=64, F=O=128, E=3, 2 layers. fp32 in memory, bf16 MFMA compute.
//
// Pipeline:
//   k_prep     : adj fp32 -> adjb bf16 [E,B,N,N]; weights -> wt bf16 [layer][4][o][f]
//                (g=0..2: W[e]^T, g=3: Wh^T)
//   k_support  : per (n-tile,b): sup[e,b,o,n] = bf16(W^T X^T + bias)  (3 GEMMs)
//                + tg[n,b,o] = sigmoid(X Wh + bh)                     (1 GEMM, fused)
//   k_agg      : out[m,b,o] = relu(sum_e adj[e,b,m,:] sup[e,b,:,o]^T)*t + x*(1-t)
//                double-buffered LDS, reg prefetch, 1 barrier/iter, K-chunk 64.
// Layer-1 h lives in d_out; layer 2 runs in-place on d_out.

typedef __bf16 bf16x8 __attribute__((ext_vector_type(8)));
typedef float f32x4 __attribute__((ext_vector_type(4)));
typedef unsigned short u16x8 __attribute__((ext_vector_type(8)));

#define MFMA16(a, b, c) __builtin_amdgcn_mfma_f32_16x16x32_bf16((a), (b), (c), 0, 0, 0)

__device__ __forceinline__ unsigned short f2bf(float f) {  // RNE
  union { float f; unsigned int i; } v;
  v.f = f;
  return (unsigned short)((v.i + 0x7FFFu + ((v.i >> 16) & 1u)) >> 16);
}

// ---------------------------------------------------------------------------
// k_prep: blocks 0..7 transpose one 128x128 weight matrix each (fp32 -> bf16
// [o][f]); all blocks then grid-stride convert adj (50.3M floats, 8/thread/iter).
// ---------------------------------------------------------------------------
__global__ __launch_bounds__(256) void k_prep(
    const float* __restrict__ adj,
    const float* __restrict__ W1, const float* __restrict__ Wh1,
    const float* __restrict__ W2, const float* __restrict__ Wh2,
    unsigned short* __restrict__ adjb, unsigned short* __restrict__ wt) {
  __shared__ unsigned short T[128 * 136];
  const int tid = threadIdx.x;
  if (blockIdx.x < 8) {
    const int layer = blockIdx.x >> 2, g = blockIdx.x & 3;
    const float* src = (g < 3) ? ((layer ? W2 : W1) + g * 16384)
                               : (layer ? Wh2 : Wh1);
    unsigned short* dst = wt + layer * 65536 + g * 16384;
#pragma unroll
    for (int i = 0; i < 16; ++i) {
      int c = i * 256 + tid, f = c >> 5, p = (c & 31) * 4;
      float4 v = *(const float4*)(src + f * 128 + p);
      T[(p + 0) * 136 + f] = f2bf(v.x);
      T[(p + 1) * 136 + f] = f2bf(v.y);
      T[(p + 2) * 136 + f] = f2bf(v.z);
      T[(p + 3) * 136 + f] = f2bf(v.w);
    }
    __syncthreads();
#pragma unroll
    for (int i = 0; i < 8; ++i) {
      int c = i * 256 + tid, o = c >> 4, p = (c & 15) * 8;
      *(uint4*)(dst + o * 128 + p) = *(const uint4*)(&T[o * 136 + p]);
    }
  }
  const long NCH = 6291456;  // 50,331,648 / 8
  for (long c = (long)blockIdx.x * 256 + tid; c < NCH; c += (long)gridDim.x * 256) {
    const float* s = adj + c * 8;
    float4 v0 = *(const float4*)s, v1 = *(const float4*)(s + 4);
    u16x8 u = { f2bf(v0.x), f2bf(v0.y), f2bf(v0.z), f2bf(v0.w),
                f2bf(v1.x), f2bf(v1.y), f2bf(v1.z), f2bf(v1.w) };
    *(u16x8*)(adjb + c * 8) = u;
  }
}

// ---------------------------------------------------------------------------
// k_support: grid (4,64) = (n-tile of 128, b), 256 threads, 2x2 wave tile.
// g=0..2: D[o,n] = W[g]^T @ X^T  -> sup (bf16, +bias)
// g=3   : D[n,o] = X @ Wh        -> tg  (fp32 sigmoid), operands swapped so
//         stores stay o-contiguous.
// ---------------------------------------------------------------------------
__global__ __launch_bounds__(256) void k_support(
    const float* __restrict__ x, const unsigned short* __restrict__ wt,
    const float* __restrict__ bias, const float* __restrict__ bh,
    unsigned short* __restrict__ sup, float* __restrict__ tg) {
  __shared__ unsigned short Xs[128 * 136];  // [n][f] bf16
  __shared__ unsigned short Ws[128 * 136];  // [o][f] bf16
  const int tid = threadIdx.x;
  const int lane = tid & 63;
  const int wv = tid >> 6;
  const int wm = wv >> 1, wn = wv & 1;
  const int l15 = lane & 15, q = lane >> 4;
  const int b = blockIdx.y;
  const int n0 = blockIdx.x * 128;

  {  // stage Xs (convert fp32 -> bf16)
    const size_t base = (size_t)n0 * 8192 + (size_t)b * 128;
#pragma unroll
    for (int i = 0; i < 16; ++i) {
      int c = i * 256 + tid, n = c >> 5, p = (c & 31) * 4;
      float4 v = *(const float4*)(x + base + (size_t)n * 8192 + p);
      ushort4 u = { f2bf(v.x), f2bf(v.y), f2bf(v.z), f2bf(v.w) };
      *(ushort4*)(&Xs[n * 136 + p]) = u;
    }
  }

  for (int g = 0; g < 4; ++g) {
    __syncthreads();  // fence Xs stage (g=0) / previous g's Ws reads
    {
      const unsigned short* wp = wt + g * 16384;
#pragma unroll
      for (int i = 0; i < 8; ++i) {
        int c = i * 256 + tid, o = c >> 4, p = (c & 15) * 8;
        *(uint4*)(&Ws[o * 136 + p]) = *(const uint4*)(wp + o * 128 + p);
      }
    }
    __syncthreads();

    const unsigned short* Am = (g < 3) ? Ws : Xs;  // MFMA A rows (m-dim)
    const unsigned short* Bn = (g < 3) ? Xs : Ws;  // MFMA B rows (n-dim)

    f32x4 acc[4][4];
#pragma unroll
    for (int i = 0; i < 4; ++i)
#pragma unroll
      for (int j = 0; j < 4; ++j) acc[i][j] = (f32x4){0.f, 0.f, 0.f, 0.f};

#pragma unroll
    for (int kt = 0; kt < 4; ++kt) {
      bf16x8 a[4], bb[4];
#pragma unroll
      for (int mt = 0; mt < 4; ++mt)
        a[mt] = *(const bf16x8*)(&Am[(wm * 64 + mt * 16 + l15) * 136 + kt * 32 + q * 8]);
#pragma unroll
      for (int nt = 0; nt < 4; ++nt)
        bb[nt] = *(const bf16x8*)(&Bn[(wn * 64 + nt * 16 + l15) * 136 + kt * 32 + q * 8]);
#pragma unroll
      for (int mt = 0; mt < 4; ++mt)
#pragma unroll
        for (int nt = 0; nt < 4; ++nt)
          acc[mt][nt] = MFMA16(a[mt], bb[nt], acc[mt][nt]);
    }

    if (g < 3) {  // sup[e,b,o,n] bf16, row=o (q*4+r), col=n (l15)
      const size_t sb = (size_t)(g * 64 + b) * 65536;
#pragma unroll
      for (int mt = 0; mt < 4; ++mt) {
        int o = wm * 64 + mt * 16 + q * 4;
#pragma unroll
        for (int nt = 0; nt < 4; ++nt) {
          int nn = n0 + wn * 64 + nt * 16 + l15;
#pragma unroll
          for (int r = 0; r < 4; ++r) {
            float v = acc[mt][nt][r] + bias[g * 128 + o + r];
            sup[sb + (size_t)(o + r) * 512 + nn] = f2bf(v);
          }
        }
      }
    } else {  // tg[n,b,o] fp32, row=n (q*4+r), col=o (l15)
#pragma unroll
      for (int mt = 0; mt < 4; ++mt) {
#pragma unroll
        for (int nt = 0; nt < 4; ++nt) {
          int o = wn * 64 + nt * 16 + l15;
#pragma unroll
          for (int r = 0; r < 4; ++r) {
            int nn = n0 + wm * 64 + mt * 16 + q * 4 + r;
            float v = acc[mt][nt][r] + bh[o];
            tg[((size_t)nn * 64 + b) * 128 + o] = 1.f / (1.f + __expf(-v));
          }
        }
      }
    }
  }
}

// ---------------------------------------------------------------------------
// k_agg: grid (8,64) = (m-tile of 64, b), 256 threads, wave w -> m rows
// [16w,16w+16), full o=128. K = 3e x 512n as 24 chunks of 64. Double-buffered
// LDS (pad 72: 16B-aligned, 2-way banks only), register prefetch one chunk
// ahead, single barrier per iteration.
// ---------------------------------------------------------------------------
__global__ __launch_bounds__(256, 2) void k_agg(
    const unsigned short* __restrict__ adjb, const unsigned short* __restrict__ sup,
    const float* __restrict__ tg, const float* __restrict__ x,
    float* __restrict__ dst) {
  __shared__ unsigned short As[2][64 * 72];
  __shared__ unsigned short Bs[2][128 * 72];
  const int tid = threadIdx.x;
  const int lane = tid & 63;
  const int wv = tid >> 6;
  const int l15 = lane & 15, q = lane >> 4;
  const int b = blockIdx.y;
  const int m0 = blockIdx.x * 64;

  const int arow = tid >> 3, acc8 = (tid & 7) * 8;  // chunk-staging coords

  uint4 ra[2], rb[4];
#define LOAD_CHUNK(it)                                                        \
  {                                                                           \
    int e_ = (it) >> 3, kt_ = (it) & 7;                                       \
    size_t ab_ = ((size_t)(e_ * 64 + b) * 512 + m0) * 512 + kt_ * 64;         \
    size_t sb_ = (size_t)(e_ * 64 + b) * 65536 + kt_ * 64;                    \
    ra[0] = *(const uint4*)(adjb + ab_ + (size_t)arow * 512 + acc8);          \
    ra[1] = *(const uint4*)(adjb + ab_ + (size_t)(arow + 32) * 512 + acc8);   \
    _Pragma("unroll") for (int i_ = 0; i_ < 4; ++i_)                          \
        rb[i_] = *(const uint4*)(sup + sb_ + (size_t)(arow + i_ * 32) * 512 + acc8); \
  }
#define STORE_CHUNK(buf)                                                      \
  {                                                                           \
    *(uint4*)(&As[buf][arow * 72 + acc8]) = ra[0];                            \
    *(uint4*)(&As[buf][(arow + 32) * 72 + acc8]) = ra[1];                     \
    _Pragma("unroll") for (int i_ = 0; i_ < 4; ++i_)                          \
        *(uint4*)(&Bs[buf][(arow + i_ * 32) * 72 + acc8]) = rb[i_];           \
  }

  f32x4 acc[8];
#pragma unroll
  for (int i = 0; i < 8; ++i) acc[i] = (f32x4){0.f, 0.f, 0.f, 0.f};

  LOAD_CHUNK(0);
  STORE_CHUNK(0);
  __syncthreads();
  int cur = 0;

  for (int it = 0; it < 24; ++it) {
    if (it + 1 < 24) LOAD_CHUNK(it + 1);  // in flight across the MFMAs
#pragma unroll
    for (int kh = 0; kh < 2; ++kh) {
      bf16x8 a = *(const bf16x8*)(&As[cur][(wv * 16 + l15) * 72 + kh * 32 + q * 8]);
#pragma unroll
      for (int ot = 0; ot < 8; ++ot) {
        bf16x8 bb = *(const bf16x8*)(&Bs[cur][(ot * 16 + l15) * 72 + kh * 32 + q * 8]);
        acc[ot] = MFMA16(a, bb, acc[ot]);
      }
    }
    if (it + 1 < 24) {
      STORE_CHUNK(cur ^ 1);  // nxt buffer: last read at it-1, fenced by that barrier
      __syncthreads();
      cur ^= 1;
    }
  }

  // Epilogue: relu + highway. C row=m (q*4+r), col=o (l15).
#pragma unroll
  for (int ot = 0; ot < 8; ++ot) {
#pragma unroll
    for (int r = 0; r < 4; ++r) {
      int m = m0 + wv * 16 + q * 4 + r;
      int o = ot * 16 + l15;
      size_t ridx = (size_t)(m * 64 + b) * 128 + o;
      float agg = acc[ot][r];
      agg = agg > 0.f ? agg : 0.f;
      float tv = tg[ridx];
      float xv = x[ridx];
      dst[ridx] = fmaf(agg, tv, xv * (1.f - tv));
    }
  }
#undef LOAD_CHUNK
#undef STORE_CHUNK
}

// ---------------------------------------------------------------------------
extern "C" void kernel_launch(void* const* d_in, const int* in_sizes, int n_in,
                              void* d_out, int out_size, void* d_ws, size_t ws_size,
                              hipStream_t stream) {
  const float* x   = (const float*)d_in[0];
  const float* adj = (const float*)d_in[1];
  const float* W1  = (const float*)d_in[2];
  const float* b1  = (const float*)d_in[3];
  const float* Wh1 = (const float*)d_in[4];
  const float* bh1 = (const float*)d_in[5];
  const float* W2  = (const float*)d_in[6];
  const float* b2  = (const float*)d_in[7];
  const float* Wh2 = (const float*)d_in[8];
  const float* bh2 = (const float*)d_in[9];
  float* out = (float*)d_out;

  char* ws = (char*)d_ws;
  unsigned short* adjb = (unsigned short*)ws;                    // 100,663,296 B
  unsigned short* sup  = (unsigned short*)(ws + 100663296);      //  25,165,824 B
  float*          tg   = (float*)(ws + 125829120);               //  16,777,216 B
  unsigned short* wt   = (unsigned short*)(ws + 142606336);      //     262,144 B

  dim3 blk(256);

  k_prep<<<dim3(3072), blk, 0, stream>>>(adj, W1, Wh1, W2, Wh2, adjb, wt);

  // Layer 1 (h -> d_out)
  k_support<<<dim3(4, 64), blk, 0, stream>>>(x, wt, b1, bh1, sup, tg);
  k_agg<<<dim3(8, 64), blk, 0, stream>>>(adjb, sup, tg, x, out);

  // Layer 2 (in-place on d_out)
  k_support<<<dim3(4, 64), blk, 0, stream>>>(out, wt + 65536, b2, bh2, sup, tg);
  k_agg<<<dim3(8, 64), blk, 0, stream>>>(adjb, sup, tg, out, out);
}